// Round 3
// baseline (252.966 us; speedup 1.0000x reference)
//
#include <hip/hip_runtime.h>
#include <math.h>

#define EPS 1e-6f
// B=2, C=256, N=32768 (32^3), g=8, heads=4, d=64

typedef __attribute__((ext_vector_type(8))) short bhalf8;
typedef __attribute__((ext_vector_type(4))) float floatx4;

__device__ __forceinline__ unsigned short f2bf(float f) {
    union { float f; unsigned u; } v; v.f = f;
    unsigned r = (v.u + 0x7fffu + ((v.u >> 16) & 1u)) >> 16;
    return (unsigned short)r;
}
__device__ __forceinline__ float bflo(unsigned u) {
    union { unsigned x; float f; } v; v.x = u << 16; return v.f;
}
__device__ __forceinline__ float bfhi(unsigned u) {
    union { unsigned x; float f; } v; v.x = u & 0xffff0000u; return v.f;
}

// ---------------- K1: weight prep (blocks 0..255) + avg-pool (blocks 256..767) ----------------
// W1b/W2b chunked bf16 [kc][o][32]: W1b[kc*8192 + o*32 + (c&31)], kc = c>>5
// A[o] = sum_c q_w[o][c]*nq_w[c],  Bc[o] = sum_c q_w[o][c]*nq_b[c]
__global__ void pre1(const float* __restrict__ q_w,
                     const float* __restrict__ proj_w,
                     const float* __restrict__ nq_w,
                     const float* __restrict__ nq_b,
                     unsigned short* __restrict__ W1b,
                     unsigned short* __restrict__ W2b,
                     float* __restrict__ A, float* __restrict__ Bc,
                     const float* __restrict__ x1, float* __restrict__ tokens) {
    if (blockIdx.x < 256) {
        int o = blockIdx.x;
        int c = threadIdx.x;
        float qv = q_w[o * 256 + c];
        float pv = proj_w[o * 256 + c];
        float w1 = qv * nq_w[c];
        int kc = c >> 5, kk = c & 31;
        W1b[kc * 8192 + o * 32 + kk] = f2bf(w1);
        W2b[kc * 8192 + o * 32 + kk] = f2bf(pv);
        float bcv = qv * nq_b[c];
        __shared__ float sA[4], sB[4];
        float a = w1, b = bcv;
        for (int off = 32; off > 0; off >>= 1) {
            a += __shfl_down(a, off);
            b += __shfl_down(b, off);
        }
        int wave = threadIdx.x >> 6, lane = threadIdx.x & 63;
        if (lane == 0) { sA[wave] = a; sB[wave] = b; }
        __syncthreads();
        if (threadIdx.x == 0) {
            A[o]  = sA[0] + sA[1] + sA[2] + sA[3];
            Bc[o] = sB[0] + sB[1] + sB[2] + sB[3];
        }
    } else {
        int bc = blockIdx.x - 256;  // b*256 + c
        const float* base = x1 + (size_t)bc * 4096;
        int wave = threadIdx.x >> 6;
        int lane = threadIdx.x & 63;
        int doff = lane >> 3, hoff = lane & 7;
        for (int t = wave * 2; t < wave * 2 + 2; ++t) {
            int gd = t >> 2, gh = (t >> 1) & 1, gw = t & 1;
            const float* p = base + (gd * 8 + doff) * 256 + (gh * 8 + hoff) * 16 + gw * 8;
            float4 v0 = *(const float4*)p;
            float4 v1 = *(const float4*)(p + 4);
            float s = v0.x + v0.y + v0.z + v0.w + v1.x + v1.y + v1.z + v1.w;
            for (int off = 32; off > 0; off >>= 1) s += __shfl_down(s, off);
            if (lane == 0) tokens[bc * 8 + t] = s * (1.0f / 512.0f);
        }
    }
}

// ---------------- K2: dwconv + residual + LN + k/v projection, merged ----------------
__global__ void tokens_all(const float* __restrict__ tokens,
                           const float* __restrict__ dw_w,
                           const float* __restrict__ nkv_w,
                           const float* __restrict__ nkv_b,
                           const float* __restrict__ k_w,
                           const float* __restrict__ v_w,
                           unsigned short* __restrict__ kkb,
                           float* __restrict__ vv) {
    int b = blockIdx.x >> 6;
    int og = blockIdx.x & 63;
    int c = threadIdx.x;
    __shared__ float t2[256][9];
    __shared__ float u8[8], r8[8];
    float t[8];
    #pragma unroll
    for (int g = 0; g < 8; ++g) t[g] = tokens[(b * 256 + c) * 8 + g];
    float w[27];
    #pragma unroll
    for (int i = 0; i < 27; ++i) w[i] = dw_w[c * 27 + i];
    #pragma unroll
    for (int z = 0; z < 2; ++z)
    #pragma unroll
    for (int y = 0; y < 2; ++y)
    #pragma unroll
    for (int x = 0; x < 2; ++x) {
        float s = 0.f;
        #pragma unroll
        for (int i = 0; i < 3; ++i) {
            int nz = z + i - 1; if (nz < 0 || nz > 1) continue;
            #pragma unroll
            for (int j = 0; j < 3; ++j) {
                int ny = y + j - 1; if (ny < 0 || ny > 1) continue;
                #pragma unroll
                for (int l = 0; l < 3; ++l) {
                    int nx = x + l - 1; if (nx < 0 || nx > 1) continue;
                    s += w[(i * 3 + j) * 3 + l] * t[nz * 4 + ny * 2 + nx];
                }
            }
        }
        int g = z * 4 + y * 2 + x;
        t2[c][g] = t[g] + s;
    }
    __syncthreads();
    if (c < 8) {
        float su = 0.f, sq = 0.f;
        for (int cc = 0; cc < 256; ++cc) { float v = t2[cc][c]; su += v; sq += v * v; }
        float u = su * (1.f / 256.f);
        float var = sq * (1.f / 256.f) - u * u;
        u8[c] = u;
        r8[c] = rsqrtf(var + EPS);
    }
    __syncthreads();
    int wv = threadIdx.x >> 6;
    int lane = threadIdx.x & 63;
    int o = og * 4 + wv;
    float acck[8] = {0,0,0,0,0,0,0,0}, accv[8] = {0,0,0,0,0,0,0,0};
    #pragma unroll
    for (int i = 0; i < 4; ++i) {
        int cc = lane + 64 * i;
        float kw = k_w[o * 256 + cc];
        float vw = v_w[o * 256 + cc];
        float nw = nkv_w[cc], nb2 = nkv_b[cc];
        #pragma unroll
        for (int g = 0; g < 8; ++g) {
            float tv = t2[cc][g];
            acck[g] += kw * (nw * (tv - u8[g]) * r8[g] + nb2);
            accv[g] += vw * tv;
        }
    }
    #pragma unroll
    for (int g = 0; g < 8; ++g)
        for (int off = 32; off > 0; off >>= 1) {
            acck[g] += __shfl_down(acck[g], off);
            accv[g] += __shfl_down(accv[g], off);
        }
    if (lane == 0) {
        #pragma unroll
        for (int g = 0; g < 8; ++g) {
            kkb[b * 2048 + o * 8 + g] = f2bf(acck[g]);
            vv[b * 2048 + (o >> 6) * 512 + g * 64 + (o & 63)] = accv[g];
        }
    }
}

// ---------------- K3: fully fused, 8 waves x 64 positions, 3 blocks/CU (24 waves) ----------------
// W L2 traffic halved vs 32-pos tiles (full W1b+W2b streamed once per 64 positions).
// LDS 51712 B -> 3 blocks/CU. 4 barriers:
//   B1 staging->GEMM1, B2 GEMM1(XQ reads done)->epilogue overwrite + us/rs publish,
//   B2b epilogue q->attention (cross-wave: attn wave w reads head w&3 = channels
//       [64(w&3),+64) but epilogue wave w wrote [32w,+32) -- MUST barrier; this was
//       the round-2 race), B3 attention out->GEMM2.
// XQ tile (x AND q): [64 n][256 c] bf16, swizzled-256:
//   ushort idx = n*256 + ((gl ^ sw(n))<<3) + (c&7), gl = c>>3 (0..31), sw(n) = ((n>>2)^n)&7.
// GEMM: wave w owns 32 output channels (o = 32w + 16t + row), t in {0,1}, nt in 0..3.
// Attention: wave w -> head h=w&3, n-half (w>>2)*32; thread (n=lane&31, dhalf=lane>>5);
//   logit halves merged with one shfl_xor(32). Wave-local after B2b.
__global__ __launch_bounds__(512, 6)
void fused2(const float* __restrict__ x2,
            const unsigned short* __restrict__ W1b,
            const unsigned short* __restrict__ W2b,
            const float* __restrict__ Ag, const float* __restrict__ Bg,
            const unsigned short* __restrict__ kkb,
            const float* __restrict__ vvf,
            float* __restrict__ out) {
    __shared__ __align__(16) unsigned short XQ[16384];   // 32768 B
    __shared__ __align__(16) float KVP[3072];            // 12288 B: ks 4KB | vs 8KB; store scratch post-B3
    __shared__ __align__(16) float part[1024];           // 4096 B stats partials
    __shared__ __align__(16) float As[256], Bs[256];
    __shared__ float us[64], rs[64];

    const int tid = threadIdx.x;
    const int w = tid >> 6;
    const int lane = tid & 63;
    const int m = lane & 15;
    const int qd = lane >> 4;
    const int n0g = blockIdx.x * 64;
    const int b = n0g >> 15;
    const int pos0 = n0g & 32767;

    // early fetches: k/v + A/B (L2/L3-hot) and W1 kc=0 slice (overlaps staging)
    uint4 kreg;
    if (tid < 256) kreg = ((const uint4*)(kkb + b * 2048))[tid];
    float4 vreg = ((const float4*)(vvf + b * 2048))[tid];
    if (tid < 256) { As[tid] = Ag[tid]; Bs[tid] = Bg[tid]; }
    const unsigned short* w1p = W1b + (size_t)(32 * w + m) * 32 + qd * 8;
    bhalf8 af1_0 = *(const bhalf8*)(w1p);
    bhalf8 af1_1 = *(const bhalf8*)(w1p + 512);

    // ---- stage: x fp32 -> stats partials + bf16 swizzled tile + ks/vs ----
    {
        const int n4 = tid & 15, cg = tid >> 4;   // cg 0..31
        const float* xb = x2 + (size_t)b * 8388608 + pos0 + n4 * 4;
        float su[4] = {0,0,0,0}, sq[4] = {0,0,0,0};
        #pragma unroll
        for (int cc = 0; cc < 4; ++cc) {
            int p = cg + 32 * cc;   // c-pair 0..127
            int c0 = 2 * p;
            float4 a  = *(const float4*)(xb + (size_t)c0 * 32768);
            float4 bq = *(const float4*)(xb + (size_t)(c0 + 1) * 32768);
            int g = p >> 2, wsub = p & 3;
            float av[4] = {a.x, a.y, a.z, a.w};
            float bv[4] = {bq.x, bq.y, bq.z, bq.w};
            #pragma unroll
            for (int i = 0; i < 4; ++i) {
                su[i] += av[i] + bv[i];
                sq[i] += av[i] * av[i] + bv[i] * bv[i];
                int row = 4 * n4 + i;
                int swz = ((row >> 2) ^ row) & 7;
                unsigned val = (unsigned)f2bf(av[i]) | ((unsigned)f2bf(bv[i]) << 16);
                ((unsigned*)XQ)[row * 128 + ((g ^ swz) << 2) + wsub] = val;
            }
        }
        if (tid < 256) ((uint4*)KVP)[tid] = kreg;   // ks: bf16 [4 h][64 d][8 g]
        ((float4*)(KVP + 1024))[tid] = vreg;        // vs: f32 [4 h][8 g][64 d]
        // per-wave pre-reduce over the wave's 4 cg values (lanes n4, n4+16, n4+32, n4+48)
        #pragma unroll
        for (int i = 0; i < 4; ++i) {
            float a2 = su[i], q2 = sq[i];
            a2 += __shfl_down(a2, 16); q2 += __shfl_down(q2, 16);
            a2 += __shfl_down(a2, 32); q2 += __shfl_down(q2, 32);
            if (lane < 16) {
                part[w * 128 + (4 * lane + i) * 2]     = a2;
                part[w * 128 + (4 * lane + i) * 2 + 1] = q2;
            }
        }
    }
    __syncthreads();   // B1: tile + partials + ks/vs staged

    // stats (64 threads; overlaps other waves' GEMM1; published by B2)
    if (tid < 64) {
        float S = 0.f, Q = 0.f;
        #pragma unroll
        for (int w8 = 0; w8 < 8; ++w8) {
            S += part[w8 * 128 + tid * 2];
            Q += part[w8 * 128 + tid * 2 + 1];
        }
        float mu = S * (1.f / 256.f);
        us[tid] = mu;
        rs[tid] = rsqrtf(Q * (1.f / 256.f) - mu * mu + EPS);
    }

    // ---- GEMM1: q_pre[o][n] = sum_c W1[o][c] * x[c][n]; W global->VGPR double-buffered ----
    floatx4 acc[2][4];
    #pragma unroll
    for (int i = 0; i < 2; ++i)
        #pragma unroll
        for (int j = 0; j < 4; ++j)
            acc[i][j] = (floatx4){0.f, 0.f, 0.f, 0.f};
    {
        bhalf8 afb[2][2];
        afb[0][0] = af1_0; afb[0][1] = af1_1;
        #pragma unroll
        for (int kc = 0; kc < 8; ++kc) {
            if (kc < 7) {
                afb[(kc + 1) & 1][0] = *(const bhalf8*)(w1p + (kc + 1) * 8192);
                afb[(kc + 1) & 1][1] = *(const bhalf8*)(w1p + (kc + 1) * 8192 + 512);
            }
            bhalf8 bfr[4];
            #pragma unroll
            for (int nt = 0; nt < 4; ++nt) {
                int n = nt * 16 + m;
                int swz = ((n >> 2) ^ n) & 7;
                bfr[nt] = *(const bhalf8*)(XQ + n * 256 + (((4 * kc + qd) ^ swz) << 3));
            }
            #pragma unroll
            for (int t = 0; t < 2; ++t)
                #pragma unroll
                for (int nt = 0; nt < 4; ++nt)
                    acc[t][nt] = __builtin_amdgcn_mfma_f32_16x16x32_bf16(afb[kc & 1][t], bfr[nt], acc[t][nt], 0, 0, 0);
        }
    }
    // W2 kc=0 prefetch: L2 fetch overlaps epilogue + attention
    const unsigned short* w2p = W2b + (size_t)(32 * w + m) * 32 + qd * 8;
    bhalf8 af2_0 = *(const bhalf8*)(w2p);
    bhalf8 af2_1 = *(const bhalf8*)(w2p + 512);
    __syncthreads();   // B2: x-tile free; us/rs visible

    // ---- epilogue 1: LN correction, q -> XQ (swizzled, bf16) ----
    #pragma unroll
    for (int t = 0; t < 2; ++t) {
        int ob = 32 * w + 16 * t + 4 * qd;
        floatx4 Af = *(const floatx4*)&As[ob];
        floatx4 Bf = *(const floatx4*)&Bs[ob];
        int gq = ob >> 3, off = ob & 7;
        #pragma unroll
        for (int nt = 0; nt < 4; ++nt) {
            int n = nt * 16 + m;
            int swz = ((n >> 2) ^ n) & 7;
            float uv = us[n], rv = rs[n];
            unsigned p0 = (unsigned)f2bf(rv * (acc[t][nt][0] - uv * Af[0]) + Bf[0])
                        | ((unsigned)f2bf(rv * (acc[t][nt][1] - uv * Af[1]) + Bf[1]) << 16);
            unsigned p1 = (unsigned)f2bf(rv * (acc[t][nt][2] - uv * Af[2]) + Bf[2])
                        | ((unsigned)f2bf(rv * (acc[t][nt][3] - uv * Af[3]) + Bf[3]) << 16);
            uint2 val; val.x = p0; val.y = p1;
            *(uint2*)(XQ + n * 256 + ((gq ^ swz) << 3) + off) = val;
        }
    }
    __syncthreads();   // B2b: q fully written before cross-wave attention reads (round-2 fix)

    // ---- attention: wave w -> (h=w&3, n-half=(w>>2)*32); thread (n, dhalf); wave-local ----
    {
        const int h = w & 3;
        const int an = ((w >> 2) << 5) | (lane & 31);
        const int dh = lane >> 5;
        const int sw = ((an >> 2) ^ an) & 7;
        unsigned short* qrow = XQ + an * 256;
        uint4 q4[4];
        #pragma unroll
        for (int gl = 0; gl < 4; ++gl)
            q4[gl] = *(const uint4*)(qrow + (((8 * h + 4 * dh + gl) ^ sw) << 3));
        float lg[8] = {0, 0, 0, 0, 0, 0, 0, 0};
        const unsigned short* kh = (const unsigned short*)KVP + h * 512 + dh * 256;
        #pragma unroll
        for (int dp = 0; dp < 16; ++dp) {
            unsigned qq = ((const unsigned*)q4)[dp];
            float q0 = bflo(qq), q1 = bfhi(qq);
            uint4 k0 = *(const uint4*)(kh + dp * 16);
            uint4 k1 = *(const uint4*)(kh + dp * 16 + 8);
            lg[0] += q0 * bflo(k0.x); lg[1] += q0 * bfhi(k0.x);
            lg[2] += q0 * bflo(k0.y); lg[3] += q0 * bfhi(k0.y);
            lg[4] += q0 * bflo(k0.z); lg[5] += q0 * bfhi(k0.z);
            lg[6] += q0 * bflo(k0.w); lg[7] += q0 * bfhi(k0.w);
            lg[0] += q1 * bflo(k1.x); lg[1] += q1 * bfhi(k1.x);
            lg[2] += q1 * bflo(k1.y); lg[3] += q1 * bfhi(k1.y);
            lg[4] += q1 * bflo(k1.z); lg[5] += q1 * bfhi(k1.z);
            lg[6] += q1 * bflo(k1.w); lg[7] += q1 * bfhi(k1.w);
        }
        #pragma unroll
        for (int g = 0; g < 8; ++g) lg[g] += __shfl_xor(lg[g], 32);
        float mx = lg[0];
        #pragma unroll
        for (int g = 1; g < 8; ++g) mx = fmaxf(mx, lg[g]);
        float p[8], s = 0.f;
        #pragma unroll
        for (int g = 0; g < 8; ++g) { p[g] = __expf((lg[g] - mx) * 0.125f); s += p[g]; }
        float is = 1.f / s;
        #pragma unroll
        for (int g = 0; g < 8; ++g) p[g] *= is;
        float o2[32];
        #pragma unroll
        for (int j = 0; j < 32; ++j) o2[j] = 0.f;
        const float* vh = KVP + 1024 + h * 512 + dh * 32;   // [g][64 d] f32, d-half slice
        #pragma unroll
        for (int g = 0; g < 8; ++g) {
            float pg = p[g];
            #pragma unroll
            for (int j = 0; j < 8; ++j) {
                float4 v4 = *(const float4*)(vh + g * 64 + j * 4);
                o2[4 * j + 0] += pg * v4.x;
                o2[4 * j + 1] += pg * v4.y;
                o2[4 * j + 2] += pg * v4.z;
                o2[4 * j + 3] += pg * v4.w;
            }
        }
        #pragma unroll
        for (int gl = 0; gl < 4; ++gl) {
            uint4 pk;
            pk.x = (unsigned)f2bf(o2[8 * gl + 0]) | ((unsigned)f2bf(o2[8 * gl + 1]) << 16);
            pk.y = (unsigned)f2bf(o2[8 * gl + 2]) | ((unsigned)f2bf(o2[8 * gl + 3]) << 16);
            pk.z = (unsigned)f2bf(o2[8 * gl + 4]) | ((unsigned)f2bf(o2[8 * gl + 5]) << 16);
            pk.w = (unsigned)f2bf(o2[8 * gl + 6]) | ((unsigned)f2bf(o2[8 * gl + 7]) << 16);
            *(uint4*)(qrow + (((8 * h + 4 * dh + gl) ^ sw) << 3)) = pk;
        }
    }
    __syncthreads();   // B3: attn out visible; ks/vs dead -> KVP reusable

    // ---- GEMM2: out[o][n] = sum_c W2[o][c] * attn[c][n] ----
    floatx4 acc2[2][4];
    #pragma unroll
    for (int i = 0; i < 2; ++i)
        #pragma unroll
        for (int j = 0; j < 4; ++j)
            acc2[i][j] = (floatx4){0.f, 0.f, 0.f, 0.f};
    {
        bhalf8 afb[2][2];
        afb[0][0] = af2_0; afb[0][1] = af2_1;
        #pragma unroll
        for (int kc = 0; kc < 8; ++kc) {
            if (kc < 7) {
                afb[(kc + 1) & 1][0] = *(const bhalf8*)(w2p + (kc + 1) * 8192);
                afb[(kc + 1) & 1][1] = *(const bhalf8*)(w2p + (kc + 1) * 8192 + 512);
            }
            bhalf8 bfr[4];
            #pragma unroll
            for (int nt = 0; nt < 4; ++nt) {
                int n = nt * 16 + m;
                int swz = ((n >> 2) ^ n) & 7;
                bfr[nt] = *(const bhalf8*)(XQ + n * 256 + (((4 * kc + qd) ^ swz) << 3));
            }
            #pragma unroll
            for (int t = 0; t < 2; ++t)
                #pragma unroll
                for (int nt = 0; nt < 4; ++nt)
                    acc2[t][nt] = __builtin_amdgcn_mfma_f32_16x16x32_bf16(afb[kc & 1][t], bfr[nt], acc2[t][nt], 0, 0, 0);
        }
    }

    // ---- store: per-wave 16x16 LDS transpose (KVP reuse, post-B3) -> float4 stores ----
    {
        float* tb = KVP + w * 320;                 // 16 rows x 20 (pad) floats, per-wave private
        float* obase = out + (size_t)b * 8388608 + pos0;
        const int ol = lane >> 2, c4 = lane & 3;
        #pragma unroll
        for (int t = 0; t < 2; ++t) {
            #pragma unroll
            for (int nt = 0; nt < 4; ++nt) {
                #pragma unroll
                for (int rr = 0; rr < 4; ++rr)
                    tb[(qd * 4 + rr) * 20 + m] = acc2[t][nt][rr];
                float4 vo = *(const float4*)(tb + ol * 20 + c4 * 4);
                *(float4*)(obase + (size_t)(32 * w + 16 * t + ol) * 32768 + nt * 16 + c4 * 4) = vo;
            }
        }
    }
}

extern "C" void kernel_launch(void* const* d_in, const int* in_sizes, int n_in,
                              void* d_out, int out_size, void* d_ws, size_t ws_size,
                              hipStream_t stream) {
    (void)in_sizes; (void)n_in; (void)out_size; (void)ws_size;
    const float* x2     = (const float*)d_in[0];
    const float* x1_low = (const float*)d_in[1];
    const float* q_w    = (const float*)d_in[2];
    const float* k_w    = (const float*)d_in[3];
    const float* v_w    = (const float*)d_in[4];
    const float* dw_w   = (const float*)d_in[5];
    const float* proj_w = (const float*)d_in[6];
    const float* nq_w   = (const float*)d_in[7];
    const float* nq_b   = (const float*)d_in[8];
    const float* nkv_w  = (const float*)d_in[9];
    const float* nkv_b  = (const float*)d_in[10];
    float* outp = (float*)d_out;

    float* wsf = (float*)d_ws;
    float* Av  = wsf;                                        // 256
    float* Bv  = wsf + 256;                                  // 256
    float* tk  = wsf + 512;                                  // 4096
    float* vvf = wsf + 4608;                                 // 4096
    unsigned short* kkb = (unsigned short*)(wsf + 8704);     // 4096 ushorts
    unsigned short* W1b = (unsigned short*)(wsf + 10752);    // 65536 ushorts
    unsigned short* W2b = (unsigned short*)(wsf + 43520);    // 65536 ushorts

    pre1<<<768, 256, 0, stream>>>(q_w, proj_w, nq_w, nq_b, W1b, W2b, Av, Bv, x1_low, tk);
    tokens_all<<<128, 256, 0, stream>>>(tk, dw_w, nkv_w, nkv_b, k_w, v_w, kkb, vvf);
    fused2<<<1024, 512, 0, stream>>>(x2, W1b, W2b, Av, Bv, kkb, vvf, outp);
}

// Round 4
// 174.724 us; speedup vs baseline: 1.4478x; 1.4478x over previous
//
#include <hip/hip_runtime.h>
#include <math.h>

#define EPS 1e-6f
// B=2, C=256, N=32768 (32^3), g=8, heads=4, d=64

typedef __attribute__((ext_vector_type(8))) short bhalf8;
typedef __attribute__((ext_vector_type(4))) float floatx4;

__device__ __forceinline__ unsigned short f2bf(float f) {
    union { float f; unsigned u; } v; v.f = f;
    unsigned r = (v.u + 0x7fffu + ((v.u >> 16) & 1u)) >> 16;
    return (unsigned short)r;
}
__device__ __forceinline__ float bflo(unsigned u) {
    union { unsigned x; float f; } v; v.x = u << 16; return v.f;
}
__device__ __forceinline__ float bfhi(unsigned u) {
    union { unsigned x; float f; } v; v.x = u & 0xffff0000u; return v.f;
}

// ---------------- K1: weight prep (blocks 0..255) + avg-pool (blocks 256..767) ----------------
// W1b/W2b chunked bf16 [kc][o][32]: W1b[kc*8192 + o*32 + (c&31)], kc = c>>5
// A[o] = sum_c q_w[o][c]*nq_w[c],  Bc[o] = sum_c q_w[o][c]*nq_b[c]
__global__ void pre1(const float* __restrict__ q_w,
                     const float* __restrict__ proj_w,
                     const float* __restrict__ nq_w,
                     const float* __restrict__ nq_b,
                     unsigned short* __restrict__ W1b,
                     unsigned short* __restrict__ W2b,
                     float* __restrict__ A, float* __restrict__ Bc,
                     const float* __restrict__ x1, float* __restrict__ tokens) {
    if (blockIdx.x < 256) {
        int o = blockIdx.x;
        int c = threadIdx.x;
        float qv = q_w[o * 256 + c];
        float pv = proj_w[o * 256 + c];
        float w1 = qv * nq_w[c];
        int kc = c >> 5, kk = c & 31;
        W1b[kc * 8192 + o * 32 + kk] = f2bf(w1);
        W2b[kc * 8192 + o * 32 + kk] = f2bf(pv);
        float bcv = qv * nq_b[c];
        __shared__ float sA[4], sB[4];
        float a = w1, b = bcv;
        for (int off = 32; off > 0; off >>= 1) {
            a += __shfl_down(a, off);
            b += __shfl_down(b, off);
        }
        int wave = threadIdx.x >> 6, lane = threadIdx.x & 63;
        if (lane == 0) { sA[wave] = a; sB[wave] = b; }
        __syncthreads();
        if (threadIdx.x == 0) {
            A[o]  = sA[0] + sA[1] + sA[2] + sA[3];
            Bc[o] = sB[0] + sB[1] + sB[2] + sB[3];
        }
    } else {
        int bc = blockIdx.x - 256;  // b*256 + c
        const float* base = x1 + (size_t)bc * 4096;
        int wave = threadIdx.x >> 6;
        int lane = threadIdx.x & 63;
        int doff = lane >> 3, hoff = lane & 7;
        for (int t = wave * 2; t < wave * 2 + 2; ++t) {
            int gd = t >> 2, gh = (t >> 1) & 1, gw = t & 1;
            const float* p = base + (gd * 8 + doff) * 256 + (gh * 8 + hoff) * 16 + gw * 8;
            float4 v0 = *(const float4*)p;
            float4 v1 = *(const float4*)(p + 4);
            float s = v0.x + v0.y + v0.z + v0.w + v1.x + v1.y + v1.z + v1.w;
            for (int off = 32; off > 0; off >>= 1) s += __shfl_down(s, off);
            if (lane == 0) tokens[bc * 8 + t] = s * (1.0f / 512.0f);
        }
    }
}

// ---------------- K2: dwconv + residual + LN + k/v projection, merged ----------------
__global__ void tokens_all(const float* __restrict__ tokens,
                           const float* __restrict__ dw_w,
                           const float* __restrict__ nkv_w,
                           const float* __restrict__ nkv_b,
                           const float* __restrict__ k_w,
                           const float* __restrict__ v_w,
                           unsigned short* __restrict__ kkb,
                           float* __restrict__ vv) {
    int b = blockIdx.x >> 6;
    int og = blockIdx.x & 63;
    int c = threadIdx.x;
    __shared__ float t2[256][9];
    __shared__ float u8[8], r8[8];
    float t[8];
    #pragma unroll
    for (int g = 0; g < 8; ++g) t[g] = tokens[(b * 256 + c) * 8 + g];
    float w[27];
    #pragma unroll
    for (int i = 0; i < 27; ++i) w[i] = dw_w[c * 27 + i];
    #pragma unroll
    for (int z = 0; z < 2; ++z)
    #pragma unroll
    for (int y = 0; y < 2; ++y)
    #pragma unroll
    for (int x = 0; x < 2; ++x) {
        float s = 0.f;
        #pragma unroll
        for (int i = 0; i < 3; ++i) {
            int nz = z + i - 1; if (nz < 0 || nz > 1) continue;
            #pragma unroll
            for (int j = 0; j < 3; ++j) {
                int ny = y + j - 1; if (ny < 0 || ny > 1) continue;
                #pragma unroll
                for (int l = 0; l < 3; ++l) {
                    int nx = x + l - 1; if (nx < 0 || nx > 1) continue;
                    s += w[(i * 3 + j) * 3 + l] * t[nz * 4 + ny * 2 + nx];
                }
            }
        }
        int g = z * 4 + y * 2 + x;
        t2[c][g] = t[g] + s;
    }
    __syncthreads();
    if (c < 8) {
        float su = 0.f, sq = 0.f;
        for (int cc = 0; cc < 256; ++cc) { float v = t2[cc][c]; su += v; sq += v * v; }
        float u = su * (1.f / 256.f);
        float var = sq * (1.f / 256.f) - u * u;
        u8[c] = u;
        r8[c] = rsqrtf(var + EPS);
    }
    __syncthreads();
    int wv = threadIdx.x >> 6;
    int lane = threadIdx.x & 63;
    int o = og * 4 + wv;
    float acck[8] = {0,0,0,0,0,0,0,0}, accv[8] = {0,0,0,0,0,0,0,0};
    #pragma unroll
    for (int i = 0; i < 4; ++i) {
        int cc = lane + 64 * i;
        float kw = k_w[o * 256 + cc];
        float vw = v_w[o * 256 + cc];
        float nw = nkv_w[cc], nb2 = nkv_b[cc];
        #pragma unroll
        for (int g = 0; g < 8; ++g) {
            float tv = t2[cc][g];
            acck[g] += kw * (nw * (tv - u8[g]) * r8[g] + nb2);
            accv[g] += vw * tv;
        }
    }
    #pragma unroll
    for (int g = 0; g < 8; ++g)
        for (int off = 32; off > 0; off >>= 1) {
            acck[g] += __shfl_down(acck[g], off);
            accv[g] += __shfl_down(accv[g], off);
        }
    if (lane == 0) {
        #pragma unroll
        for (int g = 0; g < 8; ++g) {
            kkb[b * 2048 + o * 8 + g] = f2bf(acck[g]);
            vv[b * 2048 + (o >> 6) * 512 + g * 64 + (o & 63)] = accv[g];
        }
    }
}

// ---------------- K3: fully fused, 8 waves x 64 positions, 2 blocks/CU (16 waves) ----------------
// W L2 traffic halved vs 32-pos tiles (full W1b+W2b streamed once per 64 positions).
// __launch_bounds__(512,4): VGPR cap 128. Round-3 lesson: (512,6) capped VGPR at 85,
// spilling attention state (~350 B/thread scratch -> FETCH+WRITE tripled, 141 us).
// The 3rd block/CU is NOT worth a spill; 2 clean blocks beat 3 spilling ones.
// LDS 51712 B. 4 barriers:
//   B1 staging->GEMM1, B2 GEMM1(XQ reads done)->epilogue overwrite + us/rs publish,
//   B2b epilogue q->attention (cross-wave: attn wave w reads head w&3 = channels
//       [64(w&3),+64) but epilogue wave w wrote [32w,+32)), B3 attention out->GEMM2.
// XQ tile (x AND q): [64 n][256 c] bf16, swizzled-256:
//   ushort idx = n*256 + ((gl ^ sw(n))<<3) + (c&7), gl = c>>3 (0..31), sw(n) = ((n>>2)^n)&7.
// GEMM: wave w owns 32 output channels (o = 32w + 16t + row), t in {0,1}, nt in 0..3.
// Attention: wave w -> head h=w&3, n-half (w>>2)*32; thread (n=lane&31, dhalf=lane>>5);
//   logit halves merged with one shfl_xor(32). Wave-local after B2b.
__global__ __launch_bounds__(512, 4)
void fused2(const float* __restrict__ x2,
            const unsigned short* __restrict__ W1b,
            const unsigned short* __restrict__ W2b,
            const float* __restrict__ Ag, const float* __restrict__ Bg,
            const unsigned short* __restrict__ kkb,
            const float* __restrict__ vvf,
            float* __restrict__ out) {
    __shared__ __align__(16) unsigned short XQ[16384];   // 32768 B
    __shared__ __align__(16) float KVP[3072];            // 12288 B: ks 4KB | vs 8KB; store scratch post-B3
    __shared__ __align__(16) float part[1024];           // 4096 B stats partials
    __shared__ __align__(16) float As[256], Bs[256];
    __shared__ float us[64], rs[64];

    const int tid = threadIdx.x;
    const int w = tid >> 6;
    const int lane = tid & 63;
    const int m = lane & 15;
    const int qd = lane >> 4;
    const int n0g = blockIdx.x * 64;
    const int b = n0g >> 15;
    const int pos0 = n0g & 32767;

    // early fetches: k/v + A/B (L2/L3-hot) and W1 kc=0 slice (overlaps staging)
    uint4 kreg;
    if (tid < 256) kreg = ((const uint4*)(kkb + b * 2048))[tid];
    float4 vreg = ((const float4*)(vvf + b * 2048))[tid];
    if (tid < 256) { As[tid] = Ag[tid]; Bs[tid] = Bg[tid]; }
    const unsigned short* w1p = W1b + (size_t)(32 * w + m) * 32 + qd * 8;
    bhalf8 af1_0 = *(const bhalf8*)(w1p);
    bhalf8 af1_1 = *(const bhalf8*)(w1p + 512);

    // ---- stage: x fp32 -> stats partials + bf16 swizzled tile + ks/vs ----
    {
        const int n4 = tid & 15, cg = tid >> 4;   // cg 0..31
        const float* xb = x2 + (size_t)b * 8388608 + pos0 + n4 * 4;
        float su[4] = {0,0,0,0}, sq[4] = {0,0,0,0};
        #pragma unroll
        for (int cc = 0; cc < 4; ++cc) {
            int p = cg + 32 * cc;   // c-pair 0..127
            int c0 = 2 * p;
            float4 a  = *(const float4*)(xb + (size_t)c0 * 32768);
            float4 bq = *(const float4*)(xb + (size_t)(c0 + 1) * 32768);
            int g = p >> 2, wsub = p & 3;
            float av[4] = {a.x, a.y, a.z, a.w};
            float bv[4] = {bq.x, bq.y, bq.z, bq.w};
            #pragma unroll
            for (int i = 0; i < 4; ++i) {
                su[i] += av[i] + bv[i];
                sq[i] += av[i] * av[i] + bv[i] * bv[i];
                int row = 4 * n4 + i;
                int swz = ((row >> 2) ^ row) & 7;
                unsigned val = (unsigned)f2bf(av[i]) | ((unsigned)f2bf(bv[i]) << 16);
                ((unsigned*)XQ)[row * 128 + ((g ^ swz) << 2) + wsub] = val;
            }
        }
        if (tid < 256) ((uint4*)KVP)[tid] = kreg;   // ks: bf16 [4 h][64 d][8 g]
        ((float4*)(KVP + 1024))[tid] = vreg;        // vs: f32 [4 h][8 g][64 d]
        // per-wave pre-reduce over the wave's 4 cg values (lanes n4, n4+16, n4+32, n4+48)
        #pragma unroll
        for (int i = 0; i < 4; ++i) {
            float a2 = su[i], q2 = sq[i];
            a2 += __shfl_down(a2, 16); q2 += __shfl_down(q2, 16);
            a2 += __shfl_down(a2, 32); q2 += __shfl_down(q2, 32);
            if (lane < 16) {
                part[w * 128 + (4 * lane + i) * 2]     = a2;
                part[w * 128 + (4 * lane + i) * 2 + 1] = q2;
            }
        }
    }
    __syncthreads();   // B1: tile + partials + ks/vs staged

    // stats (64 threads; overlaps other waves' GEMM1; published by B2)
    if (tid < 64) {
        float S = 0.f, Q = 0.f;
        #pragma unroll
        for (int w8 = 0; w8 < 8; ++w8) {
            S += part[w8 * 128 + tid * 2];
            Q += part[w8 * 128 + tid * 2 + 1];
        }
        float mu = S * (1.f / 256.f);
        us[tid] = mu;
        rs[tid] = rsqrtf(Q * (1.f / 256.f) - mu * mu + EPS);
    }

    // ---- GEMM1: q_pre[o][n] = sum_c W1[o][c] * x[c][n]; W global->VGPR double-buffered ----
    floatx4 acc[2][4];
    #pragma unroll
    for (int i = 0; i < 2; ++i)
        #pragma unroll
        for (int j = 0; j < 4; ++j)
            acc[i][j] = (floatx4){0.f, 0.f, 0.f, 0.f};
    {
        bhalf8 afb[2][2];
        afb[0][0] = af1_0; afb[0][1] = af1_1;
        #pragma unroll
        for (int kc = 0; kc < 8; ++kc) {
            if (kc < 7) {
                afb[(kc + 1) & 1][0] = *(const bhalf8*)(w1p + (kc + 1) * 8192);
                afb[(kc + 1) & 1][1] = *(const bhalf8*)(w1p + (kc + 1) * 8192 + 512);
            }
            bhalf8 bfr[4];
            #pragma unroll
            for (int nt = 0; nt < 4; ++nt) {
                int n = nt * 16 + m;
                int swz = ((n >> 2) ^ n) & 7;
                bfr[nt] = *(const bhalf8*)(XQ + n * 256 + (((4 * kc + qd) ^ swz) << 3));
            }
            #pragma unroll
            for (int t = 0; t < 2; ++t)
                #pragma unroll
                for (int nt = 0; nt < 4; ++nt)
                    acc[t][nt] = __builtin_amdgcn_mfma_f32_16x16x32_bf16(afb[kc & 1][t], bfr[nt], acc[t][nt], 0, 0, 0);
        }
    }
    // W2 kc=0 prefetch: L2 fetch overlaps epilogue + attention
    const unsigned short* w2p = W2b + (size_t)(32 * w + m) * 32 + qd * 8;
    bhalf8 af2_0 = *(const bhalf8*)(w2p);
    bhalf8 af2_1 = *(const bhalf8*)(w2p + 512);
    __syncthreads();   // B2: x-tile free; us/rs visible

    // ---- epilogue 1: LN correction, q -> XQ (swizzled, bf16) ----
    #pragma unroll
    for (int t = 0; t < 2; ++t) {
        int ob = 32 * w + 16 * t + 4 * qd;
        floatx4 Af = *(const floatx4*)&As[ob];
        floatx4 Bf = *(const floatx4*)&Bs[ob];
        int gq = ob >> 3, off = ob & 7;
        #pragma unroll
        for (int nt = 0; nt < 4; ++nt) {
            int n = nt * 16 + m;
            int swz = ((n >> 2) ^ n) & 7;
            float uv = us[n], rv = rs[n];
            unsigned p0 = (unsigned)f2bf(rv * (acc[t][nt][0] - uv * Af[0]) + Bf[0])
                        | ((unsigned)f2bf(rv * (acc[t][nt][1] - uv * Af[1]) + Bf[1]) << 16);
            unsigned p1 = (unsigned)f2bf(rv * (acc[t][nt][2] - uv * Af[2]) + Bf[2])
                        | ((unsigned)f2bf(rv * (acc[t][nt][3] - uv * Af[3]) + Bf[3]) << 16);
            uint2 val; val.x = p0; val.y = p1;
            *(uint2*)(XQ + n * 256 + ((gq ^ swz) << 3) + off) = val;
        }
    }
    __syncthreads();   // B2b: q fully written before cross-wave attention reads

    // ---- attention: wave w -> (h=w&3, n-half=(w>>2)*32); thread (n, dhalf); wave-local ----
    {
        const int h = w & 3;
        const int an = ((w >> 2) << 5) | (lane & 31);
        const int dh = lane >> 5;
        const int sw = ((an >> 2) ^ an) & 7;
        unsigned short* qrow = XQ + an * 256;
        uint4 q4[4];
        #pragma unroll
        for (int gl = 0; gl < 4; ++gl)
            q4[gl] = *(const uint4*)(qrow + (((8 * h + 4 * dh + gl) ^ sw) << 3));
        float lg[8] = {0, 0, 0, 0, 0, 0, 0, 0};
        const unsigned short* kh = (const unsigned short*)KVP + h * 512 + dh * 256;
        #pragma unroll
        for (int dp = 0; dp < 16; ++dp) {
            unsigned qq = ((const unsigned*)q4)[dp];
            float q0 = bflo(qq), q1 = bfhi(qq);
            uint4 k0 = *(const uint4*)(kh + dp * 16);
            uint4 k1 = *(const uint4*)(kh + dp * 16 + 8);
            lg[0] += q0 * bflo(k0.x); lg[1] += q0 * bfhi(k0.x);
            lg[2] += q0 * bflo(k0.y); lg[3] += q0 * bfhi(k0.y);
            lg[4] += q0 * bflo(k0.z); lg[5] += q0 * bfhi(k0.z);
            lg[6] += q0 * bflo(k0.w); lg[7] += q0 * bfhi(k0.w);
            lg[0] += q1 * bflo(k1.x); lg[1] += q1 * bfhi(k1.x);
            lg[2] += q1 * bflo(k1.y); lg[3] += q1 * bfhi(k1.y);
            lg[4] += q1 * bflo(k1.z); lg[5] += q1 * bfhi(k1.z);
            lg[6] += q1 * bflo(k1.w); lg[7] += q1 * bfhi(k1.w);
        }
        #pragma unroll
        for (int g = 0; g < 8; ++g) lg[g] += __shfl_xor(lg[g], 32);
        float mx = lg[0];
        #pragma unroll
        for (int g = 1; g < 8; ++g) mx = fmaxf(mx, lg[g]);
        float p[8], s = 0.f;
        #pragma unroll
        for (int g = 0; g < 8; ++g) { p[g] = __expf((lg[g] - mx) * 0.125f); s += p[g]; }
        float is = 1.f / s;
        #pragma unroll
        for (int g = 0; g < 8; ++g) p[g] *= is;
        float o2[32];
        #pragma unroll
        for (int j = 0; j < 32; ++j) o2[j] = 0.f;
        const float* vh = KVP + 1024 + h * 512 + dh * 32;   // [g][64 d] f32, d-half slice
        #pragma unroll
        for (int g = 0; g < 8; ++g) {
            float pg = p[g];
            #pragma unroll
            for (int j = 0; j < 8; ++j) {
                float4 v4 = *(const float4*)(vh + g * 64 + j * 4);
                o2[4 * j + 0] += pg * v4.x;
                o2[4 * j + 1] += pg * v4.y;
                o2[4 * j + 2] += pg * v4.z;
                o2[4 * j + 3] += pg * v4.w;
            }
        }
        #pragma unroll
        for (int gl = 0; gl < 4; ++gl) {
            uint4 pk;
            pk.x = (unsigned)f2bf(o2[8 * gl + 0]) | ((unsigned)f2bf(o2[8 * gl + 1]) << 16);
            pk.y = (unsigned)f2bf(o2[8 * gl + 2]) | ((unsigned)f2bf(o2[8 * gl + 3]) << 16);
            pk.z = (unsigned)f2bf(o2[8 * gl + 4]) | ((unsigned)f2bf(o2[8 * gl + 5]) << 16);
            pk.w = (unsigned)f2bf(o2[8 * gl + 6]) | ((unsigned)f2bf(o2[8 * gl + 7]) << 16);
            *(uint4*)(qrow + (((8 * h + 4 * dh + gl) ^ sw) << 3)) = pk;
        }
    }
    __syncthreads();   // B3: attn out visible; ks/vs dead -> KVP reusable

    // ---- GEMM2: out[o][n] = sum_c W2[o][c] * attn[c][n] ----
    floatx4 acc2[2][4];
    #pragma unroll
    for (int i = 0; i < 2; ++i)
        #pragma unroll
        for (int j = 0; j < 4; ++j)
            acc2[i][j] = (floatx4){0.f, 0.f, 0.f, 0.f};
    {
        bhalf8 afb[2][2];
        afb[0][0] = af2_0; afb[0][1] = af2_1;
        #pragma unroll
        for (int kc = 0; kc < 8; ++kc) {
            if (kc < 7) {
                afb[(kc + 1) & 1][0] = *(const bhalf8*)(w2p + (kc + 1) * 8192);
                afb[(kc + 1) & 1][1] = *(const bhalf8*)(w2p + (kc + 1) * 8192 + 512);
            }
            bhalf8 bfr[4];
            #pragma unroll
            for (int nt = 0; nt < 4; ++nt) {
                int n = nt * 16 + m;
                int swz = ((n >> 2) ^ n) & 7;
                bfr[nt] = *(const bhalf8*)(XQ + n * 256 + (((4 * kc + qd) ^ swz) << 3));
            }
            #pragma unroll
            for (int t = 0; t < 2; ++t)
                #pragma unroll
                for (int nt = 0; nt < 4; ++nt)
                    acc2[t][nt] = __builtin_amdgcn_mfma_f32_16x16x32_bf16(afb[kc & 1][t], bfr[nt], acc2[t][nt], 0, 0, 0);
        }
    }

    // ---- store: per-wave 16x16 LDS transpose (KVP reuse, post-B3) -> float4 stores ----
    {
        float* tb = KVP + w * 320;                 // 16 rows x 20 (pad) floats, per-wave private
        float* obase = out + (size_t)b * 8388608 + pos0;
        const int ol = lane >> 2, c4 = lane & 3;
        #pragma unroll
        for (int t = 0; t < 2; ++t) {
            #pragma unroll
            for (int nt = 0; nt < 4; ++nt) {
                #pragma unroll
                for (int rr = 0; rr < 4; ++rr)
                    tb[(qd * 4 + rr) * 20 + m] = acc2[t][nt][rr];
                float4 vo = *(const float4*)(tb + ol * 20 + c4 * 4);
                *(float4*)(obase + (size_t)(32 * w + 16 * t + ol) * 32768 + nt * 16 + c4 * 4) = vo;
            }
        }
    }
}

extern "C" void kernel_launch(void* const* d_in, const int* in_sizes, int n_in,
                              void* d_out, int out_size, void* d_ws, size_t ws_size,
                              hipStream_t stream) {
    (void)in_sizes; (void)n_in; (void)out_size; (void)ws_size;
    const float* x2     = (const float*)d_in[0];
    const float* x1_low = (const float*)d_in[1];
    const float* q_w    = (const float*)d_in[2];
    const float* k_w    = (const float*)d_in[3];
    const float* v_w    = (const float*)d_in[4];
    const float* dw_w   = (const float*)d_in[5];
    const float* proj_w = (const float*)d_in[6];
    const float* nq_w   = (const float*)d_in[7];
    const float* nq_b   = (const float*)d_in[8];
    const float* nkv_w  = (const float*)d_in[9];
    const float* nkv_b  = (const float*)d_in[10];
    float* outp = (float*)d_out;

    float* wsf = (float*)d_ws;
    float* Av  = wsf;                                        // 256
    float* Bv  = wsf + 256;                                  // 256
    float* tk  = wsf + 512;                                  // 4096
    float* vvf = wsf + 4608;                                 // 4096
    unsigned short* kkb = (unsigned short*)(wsf + 8704);     // 4096 ushorts
    unsigned short* W1b = (unsigned short*)(wsf + 10752);    // 65536 ushorts
    unsigned short* W2b = (unsigned short*)(wsf + 43520);    // 65536 ushorts

    pre1<<<768, 256, 0, stream>>>(q_w, proj_w, nq_w, nq_b, W1b, W2b, Av, Bv, x1_low, tk);
    tokens_all<<<128, 256, 0, stream>>>(tk, dw_w, nkv_w, nkv_b, k_w, v_w, kkb, vvf);
    fused2<<<1024, 512, 0, stream>>>(x2, W1b, W2b, Av, Bv, kkb, vvf, outp);
}